// Round 10
// baseline (108.207 us; speedup 1.0000x reference)
//
#include <hip/hip_runtime.h>
#include <hip/hip_bf16.h>
#include <cfloat>
#include <cmath>

namespace {
constexpr int NB = 2;     // batch
constexpr int NN = 64;    // user inputs
constexpr int NC = 256;   // feature channels
constexpr int NK = 10;    // classes
constexpr float ALPHA = -1.0f / 18.0f;   // -0.5/sigma^2, sigma=3
constexpr int TMPL_FLOATS = 3 * NB * NC * NN;            // 384 KiB
constexpr int PQ  = NB * NN * (4096 + 1024 + 256);       // 688128 floats/quarter
constexpr int PL1 = NB * NN * 4096;                      // lvl1 partial base
constexpr int PL2 = PL1 + NB * NN * 1024;                // lvl2 partial base
} // namespace

// Wave-uniform fp32-vs-bf16 sniff on x0's first 2KB (R1: fp32 confirmed;
// hedge kept). fp32 low halves ~uniform bits -> bf16-exp>=137 w.p. ~1.
__device__ __forceinline__ bool sniff_f32(const void* x0) {
  const ushort4 v = ((const ushort4*)x0)[threadIdx.x & 63];
  bool bad = (((v.x >> 7) & 0xFF) >= 137) | (((v.y >> 7) & 0xFF) >= 137) |
             (((v.z >> 7) & 0xFF) >= 137) | (((v.w >> 7) & 0xFF) >= 137);
  return __ballot(bad) != 0ULL;
}

__device__ __forceinline__ float ldf(const void* p, size_t i, bool f32) {
  return f32 ? ((const float*)p)[i]
             : __bfloat162float(((const __hip_bfloat16*)p)[i]);
}
__device__ __forceinline__ float bf2f(unsigned short u) {
  return __uint_as_float((unsigned)u << 16);   // bf16 -> fp32 exact
}

// ---------------------------------------------------------------------------
// Kernel 1 (unchanged, ~4us): per (level,b,n) template, thread = channel,
// per-thread Gaussian-window loop. Output [lvl][b][c][n].
// ---------------------------------------------------------------------------
__global__ __launch_bounds__(256) void tmpl_kernel(
    const void* __restrict__ x0, const void* __restrict__ x1,
    const void* __restrict__ x2, const void* __restrict__ centers,
    const int* __restrict__ idxp, const int* __restrict__ labels,
    float* __restrict__ tmpl_t) {
  const bool f32 = sniff_f32(x0);
  const int bx  = blockIdx.x;          // 384 blocks
  const int lvl = bx >> 7;
  const int b   = (bx >> 6) & 1;
  const int n   = bx & 63;
  const int W   = 64 >> lvl;
  const int HW  = W * W;
  const float s = (float)(8 << lvl);
  const void* feat = (lvl == 0) ? x0 : (lvl == 1) ? x1 : x2;

  __shared__ float ex[64], ey[64];
  __shared__ float sh_inv;
  __shared__ int   sh_win[4];

  const int t = threadIdx.x;
  const float cx = ldf(centers, (size_t)(b * NN + n) * 2 + 0, f32);
  const float cy = ldf(centers, (size_t)(b * NN + n) * 2 + 1, f32);

  if (t < W) {
    const float dx = (float)t * s + 0.5f - cx;
    const float dy = (float)t * s + 0.5f - cy;
    ex[t] = expf(ALPHA * dx * dx);
    ey[t] = expf(ALPHA * dy * dy);
  }
  __syncthreads();

  if (t == 0) {
    const bool i64 = (labels[1] == 0);            // int64 hedge
    const int  m   = b * NN + n;
    const int  iv  = i64 ? idxp[2 * m] : idxp[m];
    float Sx = 0.f, Sy = 0.f;
    for (int i = 0; i < W; ++i) { Sx += ex[i]; Sy += ey[i]; }
    sh_inv = (iv != -1) ? 1.0f / (Sx * Sy + 1e-8f) : 0.0f;
    int cs = (int)floorf((cx - 0.5f) / s + 0.5f); cs = min(max(cs, 0), W - 1);
    int rs = (int)floorf((cy - 0.5f) / s + 0.5f); rs = min(max(rs, 0), W - 1);
    const float tx = ex[cs] * 1e-7f, ty = ey[rs] * 1e-7f;
    int clo = cs, chi = cs, rlo = rs, rhi = rs;
    while (clo > 0     && ex[clo - 1] >= tx) --clo;
    while (chi < W - 1 && ex[chi + 1] >= tx) ++chi;
    while (rlo > 0     && ey[rlo - 1] >= ty) --rlo;
    while (rhi < W - 1 && ey[rhi + 1] >= ty) ++rhi;
    sh_win[0] = clo; sh_win[1] = chi; sh_win[2] = rlo; sh_win[3] = rhi;
  }
  __syncthreads();

  const float inv = sh_inv;
  const int clo = sh_win[0], chi = sh_win[1], rlo = sh_win[2], rhi = sh_win[3];
  const size_t cbase = (size_t)(b * NC + t) * HW;
  float acc = 0.f;
  for (int r = rlo; r <= rhi; ++r) {
    float rowa = 0.f;
    for (int c = clo; c <= chi; ++c)
      rowa += ex[c] * ldf(feat, cbase + r * W + c, f32);
    acc += ey[r] * rowa;
  }
  tmpl_t[(((size_t)lvl * NB + b) * NC + t) * NN + n] = acc * inv;
}

// ---------------------------------------------------------------------------
// Kernel 2 (v8): K-split GEMM partials. Block = (256-px tile, c-quarter);
// 168 blocks (1/CU), 256 threads = 4 waves = 4 n-chunks; lane = 4 px (float4).
// Each b128 tmpl broadcast now feeds 16 FMAs (4x the work of v5 -> per-CU
// ds-issue 4096->1024 reads ~= 5us). Quarter's tmpl slice (16KB) staged in
// LDS. nch==0 wave writes the feat pass-through for its quarter's channels.
// Partials -> ws.
// ---------------------------------------------------------------------------
__global__ __launch_bounds__(256, 1) void cor_part_kernel(
    const void* __restrict__ x0, const void* __restrict__ x1,
    const void* __restrict__ x2, const float* __restrict__ tmpl_t,
    float* __restrict__ part, float* __restrict__ out) {
  const bool f32 = sniff_f32(x0);
  const int bx   = blockIdx.x;         // 168 = 42 tiles x 4 quarters
  const int tile = bx >> 2, q = bx & 3;
  int lvl, b, tl;
  if (tile < 32)      { lvl = 0; b = tile >> 4; tl = tile & 15; }
  else if (tile < 40) { const int l = tile - 32; lvl = 1; b = l >> 2; tl = l & 3; }
  else                { lvl = 2; b = tile - 40; tl = 0; }
  const int W = 64 >> lvl, HW = W * W;
  const int lane = threadIdx.x & 63;
  const int nch  = __builtin_amdgcn_readfirstlane(threadIdx.x >> 6); // 0..3
  const int px   = tl * 256 + lane * 4;
  const void* feat = (lvl == 0) ? x0 : (lvl == 1) ? x1 : x2;
  const size_t base1 = (size_t)NB * (NC + NK) * 4096;
  const size_t base2 = base1 + (size_t)NB * (NC + NK) * 1024;
  const size_t lvl_base = (lvl == 0) ? 0 : (lvl == 1) ? base1 : base2;
  float* ob = out + lvl_base + (size_t)b * (NC + NK) * HW + px;
  const int c0 = q * 64;
  const size_t pbase = (lvl == 0) ? 0 : (lvl == 1) ? PL1 : PL2;
  float* pp = part + (size_t)q * PQ + pbase + (size_t)b * NN * HW + px;

  __shared__ float tlds[64][64];       // 16 KiB: quarter's tmpl [c-c0][n]
  { // coalesced stage: 4096 floats
    const float4* s4 =
        (const float4*)(tmpl_t + ((size_t)(lvl * NB + b) * NC + c0) * NN);
    float4* d4 = (float4*)&tlds[0][0];
#pragma unroll
    for (int k = 0; k < 4; ++k)
      d4[threadIdx.x + k * 256] = s4[threadIdx.x + k * 256];
  }
  __syncthreads();

  float4 acc[16];
#pragma unroll
  for (int j = 0; j < 16; ++j) acc[j] = float4{0.f, 0.f, 0.f, 0.f};

  auto run = [&](auto loadf) {
    float4 fpre[2];                    // depth-2 float4 feat prefetch
    fpre[0] = loadf(c0);
    fpre[1] = loadf(c0 + 1);
#pragma unroll 4
    for (int i = 0; i < 64; ++i) {
      const int c = c0 + i;
      const float4 f = fpre[i & 1];
      fpre[i & 1] = loadf(min(c + 2, NC - 1));     // clamp: no OOB
      if (nch == 0) *(float4*)&ob[(size_t)c * HW] = f;  // pass-through
#pragma unroll
      for (int j = 0; j < 16; ++j) {
        const float tv = tlds[i][16 * nch + j];    // wave-uniform broadcast
        acc[j].x += tv * f.x; acc[j].y += tv * f.y;
        acc[j].z += tv * f.z; acc[j].w += tv * f.w;
      }
    }
  };
  if (f32) {
    const float4* fp4 =
        (const float4*)((const float*)feat + (size_t)b * NC * HW + px);
    const int st = HW >> 2;
    run([&](int c) { return fp4[(size_t)c * st]; });
  } else {
    const ushort4* hp4 =
        (const ushort4*)((const unsigned short*)feat + (size_t)b * NC * HW + px);
    const int st = HW >> 2;
    run([&](int c) {
      const ushort4 v = hp4[(size_t)c * st];
      return float4{bf2f(v.x), bf2f(v.y), bf2f(v.z), bf2f(v.w)};
    });
  }

#pragma unroll
  for (int j = 0; j < 16; ++j)
    *(float4*)&pp[(size_t)(16 * nch + j) * HW] = acc[j];
}

// ---------------------------------------------------------------------------
// Kernel 3: combine partials + class-max. Block = (tile, px-quarter of 64);
// 168 blocks, 256 threads = 4 waves = 4 n-chunks, lane = px. Per thread:
// 16 n x 4 q coalesced loads -> per-wave class max -> LDS -> wave 0 writes
// the 10 cor channels (v5's proven epilogue shape).
// ---------------------------------------------------------------------------
__global__ __launch_bounds__(256) void combine_kernel(
    const int* __restrict__ labels, const float* __restrict__ part,
    float* __restrict__ out) {
  const int bx   = blockIdx.x;         // 168 = 42 tiles x 4 px-quarters
  const int tile = bx >> 2, pq = bx & 3;
  int lvl, b, tl;
  if (tile < 32)      { lvl = 0; b = tile >> 4; tl = tile & 15; }
  else if (tile < 40) { const int l = tile - 32; lvl = 1; b = l >> 2; tl = l & 3; }
  else                { lvl = 2; b = tile - 40; tl = 0; }
  const int W = 64 >> lvl, HW = W * W;
  const int lane = threadIdx.x & 63;
  const int nch  = __builtin_amdgcn_readfirstlane(threadIdx.x >> 6);
  const int px   = tl * 256 + pq * 64 + lane;
  const size_t base1 = (size_t)NB * (NC + NK) * 4096;
  const size_t base2 = base1 + (size_t)NB * (NC + NK) * 1024;
  const size_t lvl_base = (lvl == 0) ? 0 : (lvl == 1) ? base1 : base2;
  float* ob = out + lvl_base + (size_t)b * (NC + NK) * HW + px;
  const size_t pbase = (lvl == 0) ? 0 : (lvl == 1) ? PL1 : PL2;
  const float* pp = part + pbase + (size_t)b * NN * HW + px;

  __shared__ int   lab[NN];
  __shared__ float kmb[4][NK][64];
  if (threadIdx.x < NN) {
    const bool i64 = (labels[1] == 0);           // int64 hedge
    const int  m   = b * NN + threadIdx.x;
    lab[threadIdx.x] = i64 ? labels[2 * m] : labels[m];
  }
  __syncthreads();

  float km[NK];
#pragma unroll
  for (int k = 0; k < NK; ++k) km[k] = -FLT_MAX;
#pragma unroll 4
  for (int i = 0; i < 16; ++i) {
    const int n = 16 * nch + i;
    const size_t o = (size_t)n * HW;
    const float tot = pp[o] + pp[(size_t)PQ + o] + pp[2 * (size_t)PQ + o]
                    + pp[3 * (size_t)PQ + o];
    const int L = lab[n];
#pragma unroll
    for (int kk = 1; kk <= NK; ++kk)
      if (L == kk) km[kk - 1] = fmaxf(km[kk - 1], tot);
  }
#pragma unroll
  for (int k = 0; k < NK; ++k) kmb[nch][k][lane] = km[k];
  __syncthreads();

  if (nch == 0) {
#pragma unroll
    for (int k = 0; k < NK; ++k) {
      const float m = fmaxf(fmaxf(kmb[0][k][lane], kmb[1][k][lane]),
                            fmaxf(kmb[2][k][lane], kmb[3][k][lane]));
      ob[(size_t)(NC + k) * HW] = (m == -FLT_MAX) ? 0.f : m;   // absent -> 0
    }
  }
}

extern "C" void kernel_launch(void* const* d_in, const int* in_sizes, int n_in,
                              void* d_out, int out_size, void* d_ws, size_t ws_size,
                              hipStream_t stream) {
  const void* x0 = d_in[0];
  const void* x1 = d_in[1];
  const void* x2 = d_in[2];
  const void* ce = d_in[3];
  const int* idxp   = (const int*)d_in[4];
  const int* labels = (const int*)d_in[5];
  float* tmpl = (float*)d_ws;                          // 384 KiB
  float* part = tmpl + TMPL_FLOATS;                    // 10.5 MiB partials
  float* out  = (float*)d_out;

  tmpl_kernel<<<3 * NB * NN, 256, 0, stream>>>(x0, x1, x2, ce, idxp, labels, tmpl);
  cor_part_kernel<<<168, 256, 0, stream>>>(x0, x1, x2, tmpl, part, out);
  combine_kernel<<<168, 256, 0, stream>>>(labels, part, out);
}